// Round 10
// baseline (193.015 us; speedup 1.0000x reference)
//
#include <hip/hip_runtime.h>

// Round 15 = round 14 + EARLY-CLOBBER fix on ds_read4 outputs.
// r14's absmax failure (2.5e-13, timing-sparse corruption) was the
// multi-instruction asm with plain "=v" outputs: regalloc may alias an
// output quad with the address input %4; when the DS queue stalls issue,
// instr 1's data return clobbers the address before instrs 2-4 read it.
// "=&v" forbids the aliasing. Everything else unchanged from r13/r14:
// r11's structure (E=1 bond/lane, K=2 batches packed in v2f, 2 waves/SIMD,
// balanced DS 288 cy ~ VALU 288 cy per site) + hand-pinned LDS pipeline:
// issue site j+1's 4 ds_read_b128 -> s_waitcnt lgkmcnt(4) (counted, never
// 0 mid-loop) -> sched_barrier(0) (rule #18) -> compute site j from regs.
// x preloaded per chunk and drained (lgkmcnt(0)) before the weight
// pipeline so manual counts are exact. CST=20 scatter (0 bank conflicts),
// op_sel site_step, staging, combine all r11-verbatim (absmax 8.7e-19).

#define NSITES 784
#define DIM    8
#define ODIM   10
#define LABEL  392
#define WSITE  160   // floats per staged site: 8 columns * 20
#define CST    20    // column stride: col e at banks (20e mod 32)
#define XPST   34    // x pair-row stride: 16 sites * 2 + 2 pad

typedef float v2f __attribute__((ext_vector_type(2)));
typedef float v4f __attribute__((ext_vector_type(4)));

// quad_perm / row_half_mirror rotations (e = lane&7)
__device__ __forceinline__ float dpp_q1(float s){float d;asm("v_mov_b32_dpp %0, %1 quad_perm:[1,0,3,2] row_mask:0xf bank_mask:0xf":"=v"(d):"v"(s));return d;}
__device__ __forceinline__ float dpp_q2(float s){float d;asm("v_mov_b32_dpp %0, %1 quad_perm:[2,3,0,1] row_mask:0xf bank_mask:0xf":"=v"(d):"v"(s));return d;}
__device__ __forceinline__ float dpp_q3(float s){float d;asm("v_mov_b32_dpp %0, %1 quad_perm:[3,2,1,0] row_mask:0xf bank_mask:0xf":"=v"(d):"v"(s));return d;}
__device__ __forceinline__ float dpp_x7(float s){float d;asm("v_mov_b32_dpp %0, %1 row_half_mirror row_mask:0xf bank_mask:0xf":"=v"(d):"v"(s));return d;}

__device__ __forceinline__ v2f pk_fma(v2f a, v2f b, v2f c){v2f d;asm("v_pk_fma_f32 %0,%1,%2,%3":"=v"(d):"v"(a),"v"(b),"v"(c));return d;}
__device__ __forceinline__ v2f pk_sub(v2f a, v2f b){v2f d;asm("v_pk_add_f32 %0,%1,%2 neg_lo:[0,1] neg_hi:[0,1]":"=v"(d):"v"(a),"v"(b));return d;}
// src1 broadcast: both result halves read the SAME 32-bit half of src1
__device__ __forceinline__ v2f pk_mul_blo(v2f a, v2f b){v2f d;asm("v_pk_mul_f32 %0,%1,%2 op_sel:[0,0] op_sel_hi:[1,0]":"=v"(d):"v"(a),"v"(b));return d;}
__device__ __forceinline__ v2f pk_fma_blo(v2f a, v2f b, v2f c){v2f d;asm("v_pk_fma_f32 %0,%1,%2,%3 op_sel:[0,0,0] op_sel_hi:[1,0,1]":"=v"(d):"v"(a),"v"(b),"v"(c));return d;}
__device__ __forceinline__ v2f pk_fma_bhi(v2f a, v2f b, v2f c){v2f d;asm("v_pk_fma_f32 %0,%1,%2,%3 op_sel:[0,1,0] op_sel_hi:[1,1,1]":"=v"(d):"v"(a),"v"(b),"v"(c));return d;}

__device__ __forceinline__ v2f XY4(v4f q){ v2f r; r.x = q.x; r.y = q.y; return r; }
__device__ __forceinline__ v2f ZW4(v4f q){ v2f r; r.x = q.z; r.y = q.w; return r; }

// LDS byte address for inline-asm ds ops (generic LDS pointer: low 32 = offset)
__device__ __forceinline__ unsigned lds_off(const void* p) {
    return (unsigned)(unsigned long long)p;
}
// issue 4 ds_read_b128 (one site's 16-float weight column).
// "=&v": outputs written before later instructions re-read %4 -> must not
// alias the address register (r14's corruption).
__device__ __forceinline__ void ds_read4(unsigned a, v4f& r0, v4f& r1, v4f& r2, v4f& r3) {
    asm volatile("ds_read_b128 %0, %4 offset:0\n\t"
                 "ds_read_b128 %1, %4 offset:16\n\t"
                 "ds_read_b128 %2, %4 offset:32\n\t"
                 "ds_read_b128 %3, %4 offset:48"
                 : "=&v"(r0), "=&v"(r1), "=&v"(r2), "=&v"(r3) : "v"(a));
}

// One MPS site for 2 packed batches; lane owns output bond e. Weights in regs.
// r0/r1 = f0 m0..3 / m4..7 ; r2/r3 = f1. Verified in r11 (absmax 8.7e-19).
__device__ __forceinline__ v2f site_step(v2f v, v4f r0, v4f r1, v4f r2, v4f r3, v2f pp) {
    v2f t1; t1.x = dpp_q1(v.x);  t1.y = dpp_q1(v.y);   // v[e^1]
    v2f t2; t2.x = dpp_q2(v.x);  t2.y = dpp_q2(v.y);   // v[e^2]
    v2f t3; t3.x = dpp_q3(v.x);  t3.y = dpp_q3(v.y);   // v[e^3]
    v2f t7; t7.x = dpp_x7(v.x);  t7.y = dpp_x7(v.y);   // v[e^7]
    v2f t6; t6.x = dpp_q1(t7.x); t6.y = dpp_q1(t7.y);  // v[e^6]
    v2f t5; t5.x = dpp_q2(t7.x); t5.y = dpp_q2(t7.y);  // v[e^5]
    v2f t4; t4.x = dpp_q3(t7.x); t4.y = dpp_q3(t7.y);  // v[e^4]
    v2f a0 = pk_mul_blo(v,  XY4(r0));
    a0 = pk_fma_bhi(t1, XY4(r0), a0);
    a0 = pk_fma_blo(t2, ZW4(r0), a0);
    a0 = pk_fma_bhi(t3, ZW4(r0), a0);
    a0 = pk_fma_blo(t4, XY4(r1), a0);
    a0 = pk_fma_bhi(t5, XY4(r1), a0);
    a0 = pk_fma_blo(t6, ZW4(r1), a0);
    a0 = pk_fma_bhi(t7, ZW4(r1), a0);
    v2f a1 = pk_mul_blo(v,  XY4(r2));
    a1 = pk_fma_bhi(t1, XY4(r2), a1);
    a1 = pk_fma_blo(t2, ZW4(r2), a1);
    a1 = pk_fma_bhi(t3, ZW4(r2), a1);
    a1 = pk_fma_blo(t4, XY4(r3), a1);
    a1 = pk_fma_bhi(t5, XY4(r3), a1);
    a1 = pk_fma_blo(t6, ZW4(r3), a1);
    a1 = pk_fma_bhi(t7, ZW4(r3), a1);
    const v2f df = pk_sub(a1, a0);
    return pk_fma(pp, df, a0);                // (1-p)a0 + p a1 per packed batch
}

__global__ __launch_bounds__(256, 2) void mps_fused(
    const float* __restrict__ x,      // [B, N]
    const float* __restrict__ w0,     // [2, D]
    const float* __restrict__ Wl,     // [391, d, f, e]
    const float* __restrict__ wlab,   // [D, 2, D, O] = 1280 floats
    const float* __restrict__ Wr,     // [390, d, f, e]
    const float* __restrict__ wlast,  // [D, 2]
    float* __restrict__ out)          // [B, O]
{
    __shared__ float wb[2][2][16 * WSITE];  // [side][buf] 40.0 KB
    __shared__ float xb[2][2][16 * XPST];   // [side][buf]  8.5 KB
    __shared__ float wl[1280];              // 5.1 KB
    __shared__ float vout[2][256];          // 2.0 KB        (~55.6 KB total)

    const int tid  = threadIdx.x;
    const int side = tid >> 7;              // waves 0-1: left, 2-3: right
    const int stid = tid & 127;
    const int w    = stid >> 6;             // wave within side 0..1
    const int lane = stid & 63;
    const int e    = lane & 7;              // owned bond index
    const int g    = lane >> 3;             // batch group 0..7
    const int pr   = w * 8 + g;             // pair-row 0..15
    const int bl0  = w * 16 + g;            // lane's two block-local batches
    const int bl1  = w * 16 + 8 + g;
    const int b0   = blockIdx.x * 32;       // 32 batches per block, grid 512

    for (int k = tid; k < 320; k += 256)
        *(float4*)&wl[k * 4] = *(const float4*)&wlab[k * 4];

    // ------- staging registers (T14: load early, write late) -------
    float4 wr[4];
    float  xr[4];

    auto stage_load = [&](int c, int nt) {
        const float* W = side == 0 ? Wl : Wr;
        #pragma unroll
        for (int r = 0; r < 4; ++r) {
            const int cid = stid + 128 * r;        // 0..511 = 16 sites x 32
            const int s   = cid >> 5;
            const int u   = cid & 31;
            if (s < nt) {
                const int row = side == 0 ? (c * 16 + s) : (389 - c * 16 - s);
                wr[r] = *(const float4*)(W + (size_t)row * 128 + u * 4);
            }
        }
        #pragma unroll
        for (int r = 0; r < 4; ++r) {
            const int cid = stid + 128 * r;        // 0..511 = 32 b x 16 s
            const int b   = cid >> 4;
            const int sx  = cid & 15;
            if (sx < nt) {
                const int col = side == 0 ? (1 + c * 16 + sx) : (782 - c * 16 - sx);
                xr[r] = x[(size_t)(b0 + b) * NSITES + col];
            }
        }
    };

    // scatter (r11-verified, 0 bank conflicts):
    //   left  W[d][f][e] -> s*160 + e*20 + f*8 + (e^d)
    //   right W[d][f][e] -> s*160 + d*20 + f*8 + (d^e)
    auto stage_write = [&](int bufi, int nt) {
        float* wdst = wb[side][bufi];
        float* xdst = xb[side][bufi];
        #pragma unroll
        for (int r = 0; r < 4; ++r) {
            const int cid = stid + 128 * r;
            const int s   = cid >> 5;
            const int u   = cid & 31;
            const int d   = u >> 2;
            const int f   = (u >> 1) & 1;
            const int e4  = (u & 1) * 4;
            if (s < nt) {
                float* dst = wdst + s * WSITE + f * 8;
                const float vals[4] = {wr[r].x, wr[r].y, wr[r].z, wr[r].w};
                #pragma unroll
                for (int k = 0; k < 4; ++k) {
                    const int ee = e4 + k;
                    if (side == 0)
                        dst[ee * CST + (ee ^ d)] = vals[k];
                    else
                        dst[d * CST + (d ^ ee)] = vals[k];
                }
            }
        }
        #pragma unroll
        for (int r = 0; r < 4; ++r) {
            const int cid  = stid + 128 * r;
            const int b    = cid >> 4;
            const int sx   = cid & 15;
            const int prw  = (b >> 4) * 8 + (b & 7);
            const int half = (b >> 3) & 1;
            if (sx < nt)
                xdst[prw * XPST + sx * 2 + half] = xr[r];
        }
    };

    // ------- boundary init: v[e] for batches bl0, bl1 -------
    v2f vv;
    if (side == 0) {
        const float p0 = x[(size_t)(b0 + bl0) * NSITES];
        const float p1 = x[(size_t)(b0 + bl1) * NSITES];
        vv.x = fmaf(1.0f - p0, w0[e], p0 * w0[DIM + e]);
        vv.y = fmaf(1.0f - p1, w0[e], p1 * w0[DIM + e]);
    } else {
        const float p0 = x[(size_t)(b0 + bl0) * NSITES + (NSITES - 1)];
        const float p1 = x[(size_t)(b0 + bl1) * NSITES + (NSITES - 1)];
        vv.x = fmaf(1.0f - p0, wlast[e * 2], p0 * wlast[e * 2 + 1]);
        vv.y = fmaf(1.0f - p1, wlast[e * 2], p1 * wlast[e * 2 + 1]);
    }

    const int nt_tail = side ? 6 : 7;

    stage_load(0, 16);
    stage_write(0, 16);
    int buf = 0;

    // 16 sites; asm-pinned LDS pipeline: preload+drain x, then double-buffered
    // weight ds_read_b128 with counted lgkmcnt(4) and sched_barrier fences.
    auto compute16 = [&](int bufi) {
        const float* wp = &wb[side][bufi][e * CST];
        const float* xp = &xb[side][bufi][pr * XPST];
        v4f xq[8];
        #pragma unroll
        for (int i = 0; i < 8; ++i)
            xq[i] = *(const v4f*)(xp + i * 4);
        asm volatile("s_waitcnt lgkmcnt(0)" ::: "memory");  // x in regs; LDS cnt = 0
        __builtin_amdgcn_sched_barrier(0);
        const unsigned base = lds_off(wp);
        v4f A0, A1, A2, A3, B0, B1, B2, B3;
        ds_read4(base, A0, A1, A2, A3);                     // site 0 -> A
        #pragma unroll
        for (int j = 0; j < 16; ++j) {
            if (j < 15) {
                const unsigned a = base + (unsigned)((j + 1) * WSITE * 4);
                if (j & 1) ds_read4(a, A0, A1, A2, A3);     // site j+1
                else       ds_read4(a, B0, B1, B2, B3);
                asm volatile("s_waitcnt lgkmcnt(4)" ::: "memory");  // site j ready
            } else {
                asm volatile("s_waitcnt lgkmcnt(0)" ::: "memory");
            }
            __builtin_amdgcn_sched_barrier(0);
            const v2f pp = (j & 1) ? ZW4(xq[j >> 1]) : XY4(xq[j >> 1]);
            if (j & 1) vv = site_step(vv, B0, B1, B2, B3, pp);
            else       vv = site_step(vv, A0, A1, A2, A3, pp);
        }
    };

    #pragma unroll 1
    for (int c = 0; c < 23; ++c) {            // chunks 0..22 (full)
        __syncthreads();                      // chunk c staged; buf^1 free
        stage_load(c + 1, 16);
        compute16(buf);
        __builtin_amdgcn_sched_barrier(0);    // keep LDS writes after compute
        stage_write(buf ^ 1, 16);
        buf ^= 1;
    }

    // chunk 23 (full) + prefetch tail chunk 24
    __syncthreads();
    stage_load(24, nt_tail);
    compute16(buf);
    __builtin_amdgcn_sched_barrier(0);
    stage_write(buf ^ 1, nt_tail);
    buf ^= 1;

    // tail chunk 24 (7 sites left / 6 sites right)
    __syncthreads();
    {
        const float* wp = &wb[side][buf][e * CST];
        const float* xp = &xb[side][buf][pr * XPST];
        for (int j = 0; j < nt_tail; ++j) {
            v4f r0 = *(const v4f*)(wp + j * WSITE + 0);
            v4f r1 = *(const v4f*)(wp + j * WSITE + 4);
            v4f r2 = *(const v4f*)(wp + j * WSITE + 8);
            v4f r3 = *(const v4f*)(wp + j * WSITE + 12);
            v2f pp; pp.x = xp[j * 2]; pp.y = xp[j * 2 + 1];
            vv = site_step(vv, r0, r1, r2, r3, pp);
        }
    }

    // ------- publish bond vectors and combine at the label site -------
    vout[side][bl0 * 8 + e] = vv.x;
    vout[side][bl1 * 8 + e] = vv.y;
    __syncthreads();

    for (int idx = tid; idx < 320; idx += 256) {   // 32 batches x 10 outputs
        const int b = idx / 10;
        const int o = idx - b * 10;
        const float p = x[(size_t)(b0 + b) * NSITES + LABEL];
        const float qq = 1.0f - p;
        const float* vl = &vout[0][b * 8];
        const float* rv = &vout[1][b * 8];
        float acc = 0.0f;
        #pragma unroll
        for (int d = 0; d < DIM; ++d) {
            const float vld = vl[d];
            #pragma unroll
            for (int ee = 0; ee < DIM; ++ee) {
                const float m = fmaf(qq, wl[((d * 2 + 0) * DIM + ee) * ODIM + o],
                                     p * wl[((d * 2 + 1) * DIM + ee) * ODIM + o]);
                acc = fmaf(vld * rv[ee], m, acc);
            }
        }
        out[(size_t)(b0 + b) * ODIM + o] = acc;
    }
}

extern "C" void kernel_launch(void* const* d_in, const int* in_sizes, int n_in,
                              void* d_out, int out_size, void* d_ws, size_t ws_size,
                              hipStream_t stream) {
    (void)in_sizes; (void)n_in; (void)d_ws; (void)ws_size; (void)out_size;
    const float* x     = (const float*)d_in[0];
    const float* w0    = (const float*)d_in[1];
    const float* Wl    = (const float*)d_in[2];
    const float* wlab  = (const float*)d_in[3];
    const float* Wr    = (const float*)d_in[4];
    const float* wlast = (const float*)d_in[5];

    mps_fused<<<512, 256, 0, stream>>>(x, w0, Wl, wlab, Wr, wlast, (float*)d_out);
}